// Round 3
// baseline (449.033 us; speedup 1.0000x reference)
//
#include <hip/hip_runtime.h>

#define N_NODES 50000
#define N_EDGES 800000
#define IN_CH 64
#define HID 128

// ---------------- CSR build ----------------

__global__ __launch_bounds__(256) void k_deg(const int* __restrict__ ei, int* __restrict__ deg) {
    int e = blockIdx.x * 256 + threadIdx.x;
    if (e < N_EDGES) {
        int d = ei[N_EDGES + e];
        if ((unsigned)d < N_NODES) atomicAdd(&deg[d], 1);
    }
}

__global__ __launch_bounds__(1024) void k_scan(const int* __restrict__ deg, int* __restrict__ offs) {
    constexpr int CH = (N_NODES + 1023) / 1024;  // 49 elements per thread
    int tid = threadIdx.x;
    int base = tid * CH;
    int lsum = 0;
    for (int i = 0; i < CH; i++) {
        int idx = base + i;
        if (idx < N_NODES) lsum += deg[idx];
    }
    int lane = tid & 63, wv = tid >> 6;
    int v = lsum;
    #pragma unroll
    for (int d = 1; d < 64; d <<= 1) {
        int t = __shfl_up(v, d);
        if (lane >= d) v += t;
    }
    __shared__ int wsum[16];
    if (lane == 63) wsum[wv] = v;
    __syncthreads();
    if (tid < 16) {
        int w = wsum[tid];
        #pragma unroll
        for (int d = 1; d < 16; d <<= 1) {
            int t = __shfl_up(w, d);
            if (tid >= d) w += t;
        }
        wsum[tid] = w;
    }
    __syncthreads();
    int excl = v - lsum + (wv > 0 ? wsum[wv - 1] : 0);
    int run = excl;
    for (int i = 0; i < CH; i++) {
        int idx = base + i;
        if (idx < N_NODES) { offs[idx] = run; run += deg[idx]; }
    }
    if (tid == 1023) offs[N_NODES] = run;  // = N_EDGES
}

__global__ __launch_bounds__(256) void k_fill(const int* __restrict__ ei, const int* __restrict__ offs,
                                              int* __restrict__ cursor, int* __restrict__ csr) {
    int e = blockIdx.x * 256 + threadIdx.x;
    if (e < N_EDGES) {
        int s = ei[e];
        int d = ei[N_EDGES + e];
        if ((unsigned)d < N_NODES && (unsigned)s < N_NODES) {
            int pos = atomicAdd(&cursor[d], 1);
            csr[offs[d] + pos] = s;
        }
    }
}

// ---------------- mean aggregation (gather over CSR), one wave per node ----------------

template <int CH>
__global__ __launch_bounds__(256) void k_agg(const float* __restrict__ feat,
                                             const int* __restrict__ csr,
                                             const int* __restrict__ offs,
                                             float* __restrict__ meanout) {
    int wid = (blockIdx.x * 256 + threadIdx.x) >> 6;  // node id
    int lane = threadIdx.x & 63;
    if (wid >= N_NODES) return;
    int beg = offs[wid], end = offs[wid + 1];
    int degn = end - beg;
    float inv = 1.0f / (float)(degn > 0 ? degn : 1);

    if (CH == 64) {
        float s = 0.f;
        int e = beg;
        for (; e + 4 <= end; e += 4) {
            int i0 = csr[e], i1 = csr[e + 1], i2 = csr[e + 2], i3 = csr[e + 3];
            float a = feat[i0 * 64 + lane];
            float b = feat[i1 * 64 + lane];
            float c = feat[i2 * 64 + lane];
            float d = feat[i3 * 64 + lane];
            s += a + b + c + d;
        }
        for (; e < end; e++) s += feat[csr[e] * 64 + lane];
        meanout[wid * 64 + lane] = s * inv;
    } else {  // CH == 128, float2 per lane
        const float2* F = (const float2*)feat;
        float sx = 0.f, sy = 0.f;
        int e = beg;
        for (; e + 4 <= end; e += 4) {
            int i0 = csr[e], i1 = csr[e + 1], i2 = csr[e + 2], i3 = csr[e + 3];
            float2 a = F[i0 * 64 + lane];
            float2 b = F[i1 * 64 + lane];
            float2 c = F[i2 * 64 + lane];
            float2 d = F[i3 * 64 + lane];
            sx += a.x + b.x + c.x + d.x;
            sy += a.y + b.y + c.y + d.y;
        }
        for (; e < end; e++) { float2 a = F[csr[e] * 64 + lane]; sx += a.x; sy += a.y; }
        float2 r; r.x = sx * inv; r.y = sy * inv;
        ((float2*)meanout)[wid * 64 + lane] = r;
    }
}

// ---------------- fp32 GEMM:  out[n,j] = sum_k Acat[n,k] * Wcat[j,k]  (+bias, opt relu) ----------------
// Acat = [A0 | A1] along K (each K1 wide), Wcat = [W0 | W1]. Tile: 64 nodes x NOUT.
// 256 threads; each computes MP nodes x 8 outputs.

template <int NOUT, int KTOT, bool DUAL, bool RELU>
__global__ __launch_bounds__(256) void k_gemm(const float* __restrict__ A0, const float* __restrict__ A1,
                                              const float* __restrict__ W0, const float* __restrict__ W1,
                                              const float* __restrict__ bias, float* __restrict__ out) {
    constexpr int K1 = DUAL ? KTOT / 2 : KTOT;
    constexpr int KC = 32;
    constexpr int NCH = KTOT / KC;
    constexpr int NJ = NOUT / 8;           // thread-columns (16 or 8)
    constexpr int MP = 64 * NJ / 256;      // nodes per thread (4 or 2)
    constexpr int ASTR = 36;               // padded A-tile stride (floats)
    constexpr int WSTR = (NOUT == 128) ? 140 : 68;  // bank-spread W-tile stride

    __shared__ float As[64 * ASTR];
    __shared__ float Ws[KC * WSTR];

    int tid = threadIdx.x;
    int tx = tid % NJ;
    int ty = tid / NJ;
    int m0 = blockIdx.x * 64;

    float acc[MP][8];
    #pragma unroll
    for (int i = 0; i < MP; i++)
        #pragma unroll
        for (int j = 0; j < 8; j++) acc[i][j] = 0.f;

    for (int ch = 0; ch < NCH; ch++) {
        int k0 = ch * KC;
        const float* Ap; const float* Wp; int ak0;
        if (DUAL && k0 >= K1) { Ap = A1; Wp = W1; ak0 = k0 - K1; }
        else                  { Ap = A0; Wp = W0; ak0 = k0; }

        __syncthreads();
        // stage A: 64 rows x 32 k  (row-major, stride 36)
        #pragma unroll
        for (int it = 0; it < 2; it++) {
            int idx = tid + it * 256;
            int n = idx >> 3, sl = idx & 7;
            int gn = m0 + n;
            float4 v = make_float4(0.f, 0.f, 0.f, 0.f);
            if (gn < N_NODES) v = *(const float4*)(Ap + (size_t)gn * K1 + ak0 + sl * 4);
            *(float4*)(As + n * ASTR + sl * 4) = v;
        }
        // stage W transposed: Ws[k][col'(j)] = W[j][ak0+k], col'(j) = j + 4*(j>>5)
        #pragma unroll
        for (int it = 0; it < NOUT * KC / 4 / 256; it++) {
            int idx = tid + it * 256;
            int sl = idx & 7, jj = idx >> 3;
            float4 w = *(const float4*)(Wp + jj * K1 + ak0 + sl * 4);
            int cb = jj + ((jj >> 5) << 2);
            Ws[(sl * 4 + 0) * WSTR + cb] = w.x;
            Ws[(sl * 4 + 1) * WSTR + cb] = w.y;
            Ws[(sl * 4 + 2) * WSTR + cb] = w.z;
            Ws[(sl * 4 + 3) * WSTR + cb] = w.w;
        }
        __syncthreads();

        #pragma unroll
        for (int k = 0; k < KC; k++) {
            float a[MP];
            #pragma unroll
            for (int mi = 0; mi < MP; mi++) {
                int n = ty * MP + mi;
                a[mi] = As[n * ASTR + k];
            }
            const float* wr = Ws + k * WSTR + tx * 8 + ((tx >> 2) << 2);
            float4 w0 = *(const float4*)wr;
            float4 w1 = *(const float4*)(wr + 4);
            #pragma unroll
            for (int mi = 0; mi < MP; mi++) {
                acc[mi][0] += a[mi] * w0.x;
                acc[mi][1] += a[mi] * w0.y;
                acc[mi][2] += a[mi] * w0.z;
                acc[mi][3] += a[mi] * w0.w;
                acc[mi][4] += a[mi] * w1.x;
                acc[mi][5] += a[mi] * w1.y;
                acc[mi][6] += a[mi] * w1.z;
                acc[mi][7] += a[mi] * w1.w;
            }
        }
    }

    int jb = tx * 8;
    float4 bv0 = *(const float4*)(bias + jb);
    float4 bv1 = *(const float4*)(bias + jb + 4);
    #pragma unroll
    for (int mi = 0; mi < MP; mi++) {
        int gn = m0 + ty * MP + mi;
        if (gn < N_NODES) {
            float4 r0, r1;
            r0.x = acc[mi][0] + bv0.x; r0.y = acc[mi][1] + bv0.y;
            r0.z = acc[mi][2] + bv0.z; r0.w = acc[mi][3] + bv0.w;
            r1.x = acc[mi][4] + bv1.x; r1.y = acc[mi][5] + bv1.y;
            r1.z = acc[mi][6] + bv1.z; r1.w = acc[mi][7] + bv1.w;
            if (RELU) {
                r0.x = fmaxf(r0.x, 0.f); r0.y = fmaxf(r0.y, 0.f);
                r0.z = fmaxf(r0.z, 0.f); r0.w = fmaxf(r0.w, 0.f);
                r1.x = fmaxf(r1.x, 0.f); r1.y = fmaxf(r1.y, 0.f);
                r1.z = fmaxf(r1.z, 0.f); r1.w = fmaxf(r1.w, 0.f);
            }
            *(float4*)(out + (size_t)gn * NOUT + jb) = r0;
            *(float4*)(out + (size_t)gn * NOUT + jb + 4) = r1;
        }
    }
}

// ---------------- launch ----------------

extern "C" void kernel_launch(void* const* d_in, const int* in_sizes, int n_in,
                              void* d_out, int out_size, void* d_ws, size_t ws_size,
                              hipStream_t stream) {
    const float* x    = (const float*)d_in[0];
    const int*   ei   = (const int*)d_in[1];   // [2, N_EDGES]: row0=src, row1=dst (int32)
    const float* W1l  = (const float*)d_in[2];
    const float* b1l  = (const float*)d_in[3];
    const float* W1r  = (const float*)d_in[4];
    const float* W2l  = (const float*)d_in[5];
    const float* b2l  = (const float*)d_in[6];
    const float* W2r  = (const float*)d_in[7];
    const float* Wrec = (const float*)d_in[8];
    const float* brec = (const float*)d_in[9];

    float* z    = (float*)d_out;                          // [N,128]
    float* xrec = (float*)d_out + (size_t)N_NODES * HID;  // [N,64]

    // workspace layout (compact; peak concurrent use ~56 MB)
    char* ws = (char*)d_ws;
    int*   deg    = (int*)(ws);                 //  0    .. 200 KB
    int*   offs   = (int*)(ws + (256u << 10));  // 256KB .. 456 KB (50001 ints)
    int*   cursor = (int*)(ws + (512u << 10));  // 512KB .. 712 KB
    int*   csr    = (int*)(ws + (768u << 10));  // 768KB .. ~4 MB (800000 ints)
    float* mean1  = (float*)(ws + (4u  << 20)); // [N,64]  4 .. 16.8 MB (dead after GEMM1)
    float* mean2  = (float*)(ws + (4u  << 20)); // [N,128] reuses mean1's region, 4 .. 29.6 MB
    float* h      = (float*)(ws + (30u << 20)); // [N,128] 30 .. 55.6 MB

    hipMemsetAsync(deg, 0, N_NODES * sizeof(int), stream);
    hipMemsetAsync(cursor, 0, N_NODES * sizeof(int), stream);

    int egrid = (N_EDGES + 255) / 256;
    int ngrid = (N_NODES + 63) / 64;

    k_deg<<<egrid, 256, 0, stream>>>(ei, deg);
    k_scan<<<1, 1024, 0, stream>>>(deg, offs);
    k_fill<<<egrid, 256, 0, stream>>>(ei, offs, cursor, csr);

    k_agg<64><<<N_NODES / 4, 256, 0, stream>>>(x, csr, offs, mean1);
    k_gemm<128, 128, true, true><<<ngrid, 256, 0, stream>>>(mean1, x, W1l, W1r, b1l, h);
    k_agg<128><<<N_NODES / 4, 256, 0, stream>>>(h, csr, offs, mean2);
    k_gemm<128, 256, true, false><<<ngrid, 256, 0, stream>>>(mean2, h, W2l, W2r, b2l, z);
    k_gemm<64, 128, false, false><<<ngrid, 256, 0, stream>>>(z, nullptr, Wrec, nullptr, brec, xrec);
}

// Round 4
// 365.763 us; speedup vs baseline: 1.2277x; 1.2277x over previous
//
#include <hip/hip_runtime.h>

#define N_NODES 50000
#define N_EDGES 800000
#define IN_CH 64
#define HID 128
#define NB_SCAN ((N_NODES + 255) / 256)   // 196 blocks

// ---------------- CSR build ----------------

__global__ __launch_bounds__(256) void k_deg(const int* __restrict__ ei, int* __restrict__ deg) {
    int e = blockIdx.x * 256 + threadIdx.x;
    if (e < N_EDGES) {
        int d = ei[N_EDGES + e];
        if ((unsigned)d < N_NODES) atomicAdd(&deg[d], 1);
    }
}

// hierarchical scan, stage 1: per-block (256 elems) scan
__global__ __launch_bounds__(256) void k_scan1(const int* __restrict__ deg,
                                               int* __restrict__ excl,
                                               int* __restrict__ bsum) {
    int gid = blockIdx.x * 256 + threadIdx.x;
    int v = (gid < N_NODES) ? deg[gid] : 0;
    int lane = threadIdx.x & 63, wv = threadIdx.x >> 6;
    int s = v;
    #pragma unroll
    for (int d = 1; d < 64; d <<= 1) {
        int t = __shfl_up(s, d);
        if (lane >= d) s += t;
    }
    __shared__ int wsum[4];
    if (lane == 63) wsum[wv] = s;
    __syncthreads();
    int add = 0;
    #pragma unroll
    for (int w = 0; w < 4; w++) add += (w < wv) ? wsum[w] : 0;
    s += add;
    if (gid < N_NODES) excl[gid] = s - v;
    if (threadIdx.x == 255) bsum[blockIdx.x] = s;
}

// stage 2: scan the 196 block sums (single block), write grand total to offs[N]
__global__ __launch_bounds__(256) void k_scan2(const int* __restrict__ bsum,
                                               int* __restrict__ bpre,
                                               int* __restrict__ offs) {
    int tid = threadIdx.x;
    int v = (tid < NB_SCAN) ? bsum[tid] : 0;
    int lane = tid & 63, wv = tid >> 6;
    int s = v;
    #pragma unroll
    for (int d = 1; d < 64; d <<= 1) {
        int t = __shfl_up(s, d);
        if (lane >= d) s += t;
    }
    __shared__ int wsum[4];
    if (lane == 63) wsum[wv] = s;
    __syncthreads();
    int add = 0;
    #pragma unroll
    for (int w = 0; w < 4; w++) add += (w < wv) ? wsum[w] : 0;
    s += add;
    if (tid < NB_SCAN) bpre[tid] = s - v;
    if (tid == NB_SCAN - 1) offs[N_NODES] = s;
}

// stage 3: offs[i] = excl[i] + block_prefix
__global__ __launch_bounds__(256) void k_scan3(const int* __restrict__ excl,
                                               const int* __restrict__ bpre,
                                               int* __restrict__ offs) {
    int gid = blockIdx.x * 256 + threadIdx.x;
    if (gid < N_NODES) offs[gid] = excl[gid] + bpre[blockIdx.x];
}

__global__ __launch_bounds__(256) void k_fill(const int* __restrict__ ei, const int* __restrict__ offs,
                                              int* __restrict__ cursor, int* __restrict__ csr) {
    int e = blockIdx.x * 256 + threadIdx.x;
    if (e < N_EDGES) {
        int s = ei[e];
        int d = ei[N_EDGES + e];
        if ((unsigned)d < N_NODES && (unsigned)s < N_NODES) {
            int pos = atomicAdd(&cursor[d], 1);
            csr[offs[d] + pos] = s;
        }
    }
}

// ---------------- mean aggregation (gather over CSR), one wave per node ----------------

template <int CH>
__global__ __launch_bounds__(256) void k_agg(const float* __restrict__ feat,
                                             const int* __restrict__ csr,
                                             const int* __restrict__ offs,
                                             float* __restrict__ meanout) {
    int wid = (blockIdx.x * 256 + threadIdx.x) >> 6;  // node id
    int lane = threadIdx.x & 63;
    if (wid >= N_NODES) return;
    int beg = offs[wid], end = offs[wid + 1];
    int degn = end - beg;
    float inv = 1.0f / (float)(degn > 0 ? degn : 1);

    if (CH == 64) {
        float s = 0.f;
        int e = beg;
        for (; e + 4 <= end; e += 4) {
            int i0 = csr[e], i1 = csr[e + 1], i2 = csr[e + 2], i3 = csr[e + 3];
            float a = feat[i0 * 64 + lane];
            float b = feat[i1 * 64 + lane];
            float c = feat[i2 * 64 + lane];
            float d = feat[i3 * 64 + lane];
            s += a + b + c + d;
        }
        for (; e < end; e++) s += feat[csr[e] * 64 + lane];
        meanout[wid * 64 + lane] = s * inv;
    } else {  // CH == 128, float2 per lane
        const float2* F = (const float2*)feat;
        float sx = 0.f, sy = 0.f;
        int e = beg;
        for (; e + 4 <= end; e += 4) {
            int i0 = csr[e], i1 = csr[e + 1], i2 = csr[e + 2], i3 = csr[e + 3];
            float2 a = F[i0 * 64 + lane];
            float2 b = F[i1 * 64 + lane];
            float2 c = F[i2 * 64 + lane];
            float2 d = F[i3 * 64 + lane];
            sx += a.x + b.x + c.x + d.x;
            sy += a.y + b.y + c.y + d.y;
        }
        for (; e < end; e++) { float2 a = F[csr[e] * 64 + lane]; sx += a.x; sy += a.y; }
        float2 r; r.x = sx * inv; r.y = sy * inv;
        ((float2*)meanout)[wid * 64 + lane] = r;
    }
}

// ---------------- fp32 GEMM:  out[n,j] = sum_k Acat[n,k] * Wcat[j,k]  (+bias, opt relu) ----------------

template <int NOUT, int KTOT, bool DUAL, bool RELU>
__global__ __launch_bounds__(256) void k_gemm(const float* __restrict__ A0, const float* __restrict__ A1,
                                              const float* __restrict__ W0, const float* __restrict__ W1,
                                              const float* __restrict__ bias, float* __restrict__ out) {
    constexpr int K1 = DUAL ? KTOT / 2 : KTOT;
    constexpr int KC = 32;
    constexpr int NCH = KTOT / KC;
    constexpr int NJ = NOUT / 8;           // thread-columns (16 or 8)
    constexpr int MP = 64 * NJ / 256;      // nodes per thread (4 or 2)
    constexpr int ASTR = 36;               // padded A-tile stride (floats)
    constexpr int WSTR = (NOUT == 128) ? 140 : 68;  // bank-spread W-tile stride

    __shared__ float As[64 * ASTR];
    __shared__ float Ws[KC * WSTR];

    int tid = threadIdx.x;
    int tx = tid % NJ;
    int ty = tid / NJ;
    int m0 = blockIdx.x * 64;

    float acc[MP][8];
    #pragma unroll
    for (int i = 0; i < MP; i++)
        #pragma unroll
        for (int j = 0; j < 8; j++) acc[i][j] = 0.f;

    for (int ch = 0; ch < NCH; ch++) {
        int k0 = ch * KC;
        const float* Ap; const float* Wp; int ak0;
        if (DUAL && k0 >= K1) { Ap = A1; Wp = W1; ak0 = k0 - K1; }
        else                  { Ap = A0; Wp = W0; ak0 = k0; }

        __syncthreads();
        // stage A: 64 rows x 32 k  (row-major, stride 36)
        #pragma unroll
        for (int it = 0; it < 2; it++) {
            int idx = tid + it * 256;
            int n = idx >> 3, sl = idx & 7;
            int gn = m0 + n;
            float4 v = make_float4(0.f, 0.f, 0.f, 0.f);
            if (gn < N_NODES) v = *(const float4*)(Ap + (size_t)gn * K1 + ak0 + sl * 4);
            *(float4*)(As + n * ASTR + sl * 4) = v;
        }
        // stage W transposed: Ws[k][col'(j)] = W[j][ak0+k], col'(j) = j + 4*(j>>5)
        #pragma unroll
        for (int it = 0; it < NOUT * KC / 4 / 256; it++) {
            int idx = tid + it * 256;
            int sl = idx & 7, jj = idx >> 3;
            float4 w = *(const float4*)(Wp + jj * K1 + ak0 + sl * 4);
            int cb = jj + ((jj >> 5) << 2);
            Ws[(sl * 4 + 0) * WSTR + cb] = w.x;
            Ws[(sl * 4 + 1) * WSTR + cb] = w.y;
            Ws[(sl * 4 + 2) * WSTR + cb] = w.z;
            Ws[(sl * 4 + 3) * WSTR + cb] = w.w;
        }
        __syncthreads();

        #pragma unroll
        for (int k = 0; k < KC; k++) {
            float a[MP];
            #pragma unroll
            for (int mi = 0; mi < MP; mi++) {
                int n = ty * MP + mi;
                a[mi] = As[n * ASTR + k];
            }
            const float* wr = Ws + k * WSTR + tx * 8 + ((tx >> 2) << 2);
            float4 w0 = *(const float4*)wr;
            float4 w1 = *(const float4*)(wr + 4);
            #pragma unroll
            for (int mi = 0; mi < MP; mi++) {
                acc[mi][0] += a[mi] * w0.x;
                acc[mi][1] += a[mi] * w0.y;
                acc[mi][2] += a[mi] * w0.z;
                acc[mi][3] += a[mi] * w0.w;
                acc[mi][4] += a[mi] * w1.x;
                acc[mi][5] += a[mi] * w1.y;
                acc[mi][6] += a[mi] * w1.z;
                acc[mi][7] += a[mi] * w1.w;
            }
        }
    }

    int jb = tx * 8;
    float4 bv0 = *(const float4*)(bias + jb);
    float4 bv1 = *(const float4*)(bias + jb + 4);
    #pragma unroll
    for (int mi = 0; mi < MP; mi++) {
        int gn = m0 + ty * MP + mi;
        if (gn < N_NODES) {
            float4 r0, r1;
            r0.x = acc[mi][0] + bv0.x; r0.y = acc[mi][1] + bv0.y;
            r0.z = acc[mi][2] + bv0.z; r0.w = acc[mi][3] + bv0.w;
            r1.x = acc[mi][4] + bv1.x; r1.y = acc[mi][5] + bv1.y;
            r1.z = acc[mi][6] + bv1.z; r1.w = acc[mi][7] + bv1.w;
            if (RELU) {
                r0.x = fmaxf(r0.x, 0.f); r0.y = fmaxf(r0.y, 0.f);
                r0.z = fmaxf(r0.z, 0.f); r0.w = fmaxf(r0.w, 0.f);
                r1.x = fmaxf(r1.x, 0.f); r1.y = fmaxf(r1.y, 0.f);
                r1.z = fmaxf(r1.z, 0.f); r1.w = fmaxf(r1.w, 0.f);
            }
            *(float4*)(out + (size_t)gn * NOUT + jb) = r0;
            *(float4*)(out + (size_t)gn * NOUT + jb + 4) = r1;
        }
    }
}

// ---------------- launch ----------------

extern "C" void kernel_launch(void* const* d_in, const int* in_sizes, int n_in,
                              void* d_out, int out_size, void* d_ws, size_t ws_size,
                              hipStream_t stream) {
    const float* x    = (const float*)d_in[0];
    const int*   ei   = (const int*)d_in[1];   // [2, N_EDGES]: row0=src, row1=dst (int32)
    const float* W1l  = (const float*)d_in[2];
    const float* b1l  = (const float*)d_in[3];
    const float* W1r  = (const float*)d_in[4];
    const float* W2l  = (const float*)d_in[5];
    const float* b2l  = (const float*)d_in[6];
    const float* W2r  = (const float*)d_in[7];
    const float* Wrec = (const float*)d_in[8];
    const float* brec = (const float*)d_in[9];

    float* z    = (float*)d_out;                          // [N,128]
    float* xrec = (float*)d_out + (size_t)N_NODES * HID;  // [N,64]

    // workspace layout (peak ~58 MB)
    char* ws = (char*)d_ws;
    int*   deg    = (int*)(ws);                  //  0 .. 200 KB
    int*   offs   = (int*)(ws + (256u << 10));   // 50001 ints
    int*   cursor = (int*)(ws + (512u << 10));
    int*   excl   = (int*)(ws + (768u << 10));   // 50176 ints
    int*   bsum   = (int*)(ws + (1024u << 10));  // 196 ints
    int*   bpre   = (int*)(ws + (1028u << 10));  // 196 ints
    int*   csr    = (int*)(ws + (2u << 20));     // 800000 ints, 2 .. 5.2 MB
    float* mean1  = (float*)(ws + (6u << 20));   // [N,64]  (dead after GEMM1)
    float* mean2  = (float*)(ws + (6u << 20));   // [N,128] reuses mean1's region, 6 .. 31.6 MB
    float* h      = (float*)(ws + (32u << 20));  // [N,128] 32 .. 57.6 MB

    hipMemsetAsync(deg, 0, N_NODES * sizeof(int), stream);
    hipMemsetAsync(cursor, 0, N_NODES * sizeof(int), stream);

    int egrid = (N_EDGES + 255) / 256;
    int ngrid = (N_NODES + 63) / 64;

    k_deg<<<egrid, 256, 0, stream>>>(ei, deg);
    k_scan1<<<NB_SCAN, 256, 0, stream>>>(deg, excl, bsum);
    k_scan2<<<1, 256, 0, stream>>>(bsum, bpre, offs);
    k_scan3<<<NB_SCAN, 256, 0, stream>>>(excl, bpre, offs);
    k_fill<<<egrid, 256, 0, stream>>>(ei, offs, cursor, csr);

    k_agg<64><<<N_NODES / 4, 256, 0, stream>>>(x, csr, offs, mean1);
    k_gemm<128, 128, true, true><<<ngrid, 256, 0, stream>>>(mean1, x, W1l, W1r, b1l, h);
    k_agg<128><<<N_NODES / 4, 256, 0, stream>>>(h, csr, offs, mean2);
    k_gemm<128, 256, true, false><<<ngrid, 256, 0, stream>>>(mean2, h, W2l, W2r, b2l, z);
    k_gemm<64, 128, false, false><<<ngrid, 256, 0, stream>>>(z, nullptr, Wrec, nullptr, brec, xrec);
}

// Round 6
// 349.580 us; speedup vs baseline: 1.2845x; 1.0463x over previous
//
#include <hip/hip_runtime.h>

#define N_NODES 50000
#define N_EDGES 800000
#define IN_CH 64
#define HID 128
#define NB_SCAN ((N_NODES + 255) / 256)   // 196 blocks

typedef short short8 __attribute__((ext_vector_type(8)));
typedef float f32x4 __attribute__((ext_vector_type(4)));

static __device__ __forceinline__ unsigned short f2bf(float f) {
    unsigned u = __float_as_uint(f);
    u += 0x7FFF + ((u >> 16) & 1);   // RNE
    return (unsigned short)(u >> 16);
}
static __device__ __forceinline__ float bflo(unsigned v) { return __uint_as_float(v << 16); }
static __device__ __forceinline__ float bfhi(unsigned v) { return __uint_as_float(v & 0xFFFF0000u); }

// ---------------- fp32 -> bf16 conversion ----------------

__global__ __launch_bounds__(256) void k_cvt(const float* __restrict__ src,
                                             unsigned short* __restrict__ dst, int n4) {
    int i = blockIdx.x * 256 + threadIdx.x;
    if (i < n4) {
        float4 v = ((const float4*)src)[i];
        unsigned lo = f2bf(v.x) | ((unsigned)f2bf(v.y) << 16);
        unsigned hi = f2bf(v.z) | ((unsigned)f2bf(v.w) << 16);
        ((uint2*)dst)[i] = make_uint2(lo, hi);
    }
}

// all 5 weight matrices in one launch; dst packed at fixed offsets
__global__ __launch_bounds__(256) void k_cvt_w(const float* __restrict__ W1l, const float* __restrict__ W1r,
                                               const float* __restrict__ W2l, const float* __restrict__ W2r,
                                               const float* __restrict__ Wrec, unsigned short* __restrict__ dst) {
    int i = blockIdx.x * 256 + threadIdx.x;   // float4 units, total 14336
    int e = i * 4;
    if (e >= 57344) return;
    const float* src; int off;
    if (e < 8192)       { src = W1l;  off = 0; }
    else if (e < 16384) { src = W1r;  off = 8192; }
    else if (e < 32768) { src = W2l;  off = 16384; }
    else if (e < 49152) { src = W2r;  off = 32768; }
    else                { src = Wrec; off = 49152; }
    float4 v = *(const float4*)(src + (e - off));
    unsigned lo = f2bf(v.x) | ((unsigned)f2bf(v.y) << 16);
    unsigned hi = f2bf(v.z) | ((unsigned)f2bf(v.w) << 16);
    *(uint2*)(dst + e) = make_uint2(lo, hi);
}

// ---------------- CSR build ----------------

__global__ __launch_bounds__(256) void k_deg(const int* __restrict__ ei, int* __restrict__ deg) {
    int e = blockIdx.x * 256 + threadIdx.x;
    if (e < N_EDGES) {
        int d = ei[N_EDGES + e];
        if ((unsigned)d < N_NODES) atomicAdd(&deg[d], 1);
    }
}

__global__ __launch_bounds__(256) void k_scan1(const int* __restrict__ deg,
                                               int* __restrict__ excl,
                                               int* __restrict__ bsum) {
    int gid = blockIdx.x * 256 + threadIdx.x;
    int v = (gid < N_NODES) ? deg[gid] : 0;
    int lane = threadIdx.x & 63, wv = threadIdx.x >> 6;
    int s = v;
    #pragma unroll
    for (int d = 1; d < 64; d <<= 1) {
        int t = __shfl_up(s, d);
        if (lane >= d) s += t;
    }
    __shared__ int wsum[4];
    if (lane == 63) wsum[wv] = s;
    __syncthreads();
    int add = 0;
    #pragma unroll
    for (int w = 0; w < 4; w++) add += (w < wv) ? wsum[w] : 0;
    s += add;
    if (gid < N_NODES) excl[gid] = s - v;
    if (threadIdx.x == 255) bsum[blockIdx.x] = s;
}

__global__ __launch_bounds__(256) void k_scan2(const int* __restrict__ bsum,
                                               int* __restrict__ bpre,
                                               int* __restrict__ offs) {
    int tid = threadIdx.x;
    int v = (tid < NB_SCAN) ? bsum[tid] : 0;
    int lane = tid & 63, wv = tid >> 6;
    int s = v;
    #pragma unroll
    for (int d = 1; d < 64; d <<= 1) {
        int t = __shfl_up(s, d);
        if (lane >= d) s += t;
    }
    __shared__ int wsum[4];
    if (lane == 63) wsum[wv] = s;
    __syncthreads();
    int add = 0;
    #pragma unroll
    for (int w = 0; w < 4; w++) add += (w < wv) ? wsum[w] : 0;
    s += add;
    if (tid < NB_SCAN) bpre[tid] = s - v;
    if (tid == NB_SCAN - 1) offs[N_NODES] = s;
}

__global__ __launch_bounds__(256) void k_scan3(const int* __restrict__ excl,
                                               const int* __restrict__ bpre,
                                               int* __restrict__ offs) {
    int gid = blockIdx.x * 256 + threadIdx.x;
    if (gid < N_NODES) offs[gid] = excl[gid] + bpre[blockIdx.x];
}

__global__ __launch_bounds__(256) void k_fill(const int* __restrict__ ei, const int* __restrict__ offs,
                                              int* __restrict__ cursor, int* __restrict__ csr) {
    int e = blockIdx.x * 256 + threadIdx.x;
    if (e < N_EDGES) {
        int s = ei[e];
        int d = ei[N_EDGES + e];
        if ((unsigned)d < N_NODES && (unsigned)s < N_NODES) {
            int pos = atomicAdd(&cursor[d], 1);
            csr[offs[d] + pos] = s;
        }
    }
}

// ---------------- mean aggregation over CSR, bf16 in/out, fp32 accumulate ----------------
// CH=64: row = 128B; lanes 0-31 handle even edges, 32-63 odd edges, 2ch per lane, shfl-combine.
__global__ __launch_bounds__(256) void k_agg64b(const unsigned short* __restrict__ X,
                                                const int* __restrict__ csr,
                                                const int* __restrict__ offs,
                                                unsigned short* __restrict__ out) {
    int wid = (blockIdx.x * 256 + threadIdx.x) >> 6;
    int lane = threadIdx.x & 63;
    if (wid >= N_NODES) return;
    int beg = offs[wid], end = offs[wid + 1];
    int degn = end - beg;
    float inv = 1.0f / (float)(degn > 0 ? degn : 1);
    int half = lane >> 5, hl = lane & 31;
    float sx = 0.f, sy = 0.f;
    for (int e = beg + half; e < end; e += 2) {
        int idx = csr[e];
        unsigned v = *(const unsigned*)(X + (size_t)idx * 64 + hl * 2);
        sx += bflo(v); sy += bfhi(v);
    }
    sx += __shfl_xor(sx, 32);
    sy += __shfl_xor(sy, 32);
    if (half == 0) {
        unsigned o = f2bf(sx * inv) | ((unsigned)f2bf(sy * inv) << 16);
        *(unsigned*)(out + (size_t)wid * 64 + hl * 2) = o;
    }
}

// CH=128: row = 256B = full wave, 2ch per lane.
__global__ __launch_bounds__(256) void k_agg128b(const unsigned short* __restrict__ X,
                                                 const int* __restrict__ csr,
                                                 const int* __restrict__ offs,
                                                 unsigned short* __restrict__ out) {
    int wid = (blockIdx.x * 256 + threadIdx.x) >> 6;
    int lane = threadIdx.x & 63;
    if (wid >= N_NODES) return;
    int beg = offs[wid], end = offs[wid + 1];
    int degn = end - beg;
    float inv = 1.0f / (float)(degn > 0 ? degn : 1);
    float sx = 0.f, sy = 0.f;
    int e = beg;
    for (; e + 2 <= end; e += 2) {
        int i0 = csr[e], i1 = csr[e + 1];
        unsigned a = *(const unsigned*)(X + (size_t)i0 * 128 + lane * 2);
        unsigned b = *(const unsigned*)(X + (size_t)i1 * 128 + lane * 2);
        sx += bflo(a) + bflo(b);
        sy += bfhi(a) + bfhi(b);
    }
    if (e < end) {
        unsigned a = *(const unsigned*)(X + (size_t)csr[e] * 128 + lane * 2);
        sx += bflo(a); sy += bfhi(a);
    }
    unsigned o = f2bf(sx * inv) | ((unsigned)f2bf(sy * inv) << 16);
    *(unsigned*)(out + (size_t)wid * 128 + lane * 2) = o;
}

// ---------------- bf16 MFMA GEMM: out[n,j] = sum_k Acat[n,k]*Wcat[j,k] + bias ----------------
// Block: 4 waves x 16 rows = 64 rows. Each wave: 16 rows x NOUT via 16x16x32 MFMA,
// A and B fragments loaded straight from global (no LDS; W is L1/L2-hot).

template <int NOUT, int KTOT, bool DUAL, bool RELU, bool WF32, bool WBF16>
__global__ __launch_bounds__(256) void k_gemm_mfma(const unsigned short* __restrict__ A0,
                                                   const unsigned short* __restrict__ A1,
                                                   const unsigned short* __restrict__ W0,
                                                   const unsigned short* __restrict__ W1,
                                                   const float* __restrict__ bias,
                                                   float* __restrict__ out,
                                                   unsigned short* __restrict__ outb) {
    constexpr int K1 = DUAL ? KTOT / 2 : KTOT;
    constexpr int NF = NOUT / 16;
    int lane = threadIdx.x & 63;
    int wv = threadIdx.x >> 6;
    int m0 = blockIdx.x * 64 + wv * 16;
    int arow = m0 + (lane & 15);
    if (arow >= N_NODES) arow = N_NODES - 1;   // safe load; store guarded below
    int kg = lane >> 4;                        // k-octet 0..3

    f32x4 acc[NF] = {};

    #pragma unroll
    for (int ks = 0; ks < KTOT / 32; ks++) {
        int k0 = ks * 32;
        const unsigned short* Ap; const unsigned short* Wp; int kk;
        if (DUAL && k0 >= K1) { Ap = A1; Wp = W1; kk = k0 - K1; }
        else                  { Ap = A0; Wp = W0; kk = k0; }
        short8 a = *(const short8*)(Ap + (size_t)arow * K1 + kk + kg * 8);
        #pragma unroll
        for (int j = 0; j < NF; j++) {
            short8 b = *(const short8*)(Wp + (size_t)(j * 16 + (lane & 15)) * K1 + kk + kg * 8);
            acc[j] = __builtin_amdgcn_mfma_f32_16x16x32_bf16(a, b, acc[j], 0, 0, 0);
        }
    }

    // C/D layout: col = lane&15, row = (lane>>4)*4 + reg   [verified, learn_hip m89]
    int col = lane & 15;
    int r0 = (lane >> 4) * 4;
    #pragma unroll
    for (int j = 0; j < NF; j++) {
        float bv = bias[j * 16 + col];
        #pragma unroll
        for (int r = 0; r < 4; r++) {
            int grow = m0 + r0 + r;
            if (grow < N_NODES) {
                float v = acc[j][r] + bv;
                if (RELU) v = fmaxf(v, 0.f);
                if (WF32)  out[(size_t)grow * NOUT + j * 16 + col] = v;
                if (WBF16) outb[(size_t)grow * NOUT + j * 16 + col] = f2bf(v);
            }
        }
    }
}

// ---------------- launch ----------------

extern "C" void kernel_launch(void* const* d_in, const int* in_sizes, int n_in,
                              void* d_out, int out_size, void* d_ws, size_t ws_size,
                              hipStream_t stream) {
    const float* x    = (const float*)d_in[0];
    const int*   ei   = (const int*)d_in[1];
    const float* W1l  = (const float*)d_in[2];
    const float* b1l  = (const float*)d_in[3];
    const float* W1r  = (const float*)d_in[4];
    const float* W2l  = (const float*)d_in[5];
    const float* b2l  = (const float*)d_in[6];
    const float* W2r  = (const float*)d_in[7];
    const float* Wrec = (const float*)d_in[8];
    const float* brec = (const float*)d_in[9];

    float* z    = (float*)d_out;                          // [N,128]
    float* xrec = (float*)d_out + (size_t)N_NODES * HID;  // [N,64]

    // workspace layout (peak ~53 MB)
    char* ws = (char*)d_ws;
    int*   deg    = (int*)(ws);
    int*   offs   = (int*)(ws + (256u << 10));
    int*   cursor = (int*)(ws + (512u << 10));
    int*   excl   = (int*)(ws + (768u << 10));
    int*   bsum   = (int*)(ws + (1024u << 10));
    int*   bpre   = (int*)(ws + (1028u << 10));
    int*   csr    = (int*)(ws + (2u << 20));            // 3.2 MB
    unsigned short* wb     = (unsigned short*)(ws + (5632u << 10)); // 114 KB of bf16 weights
    unsigned short* xb     = (unsigned short*)(ws + (7u  << 20));   // [N,64]  6.4 MB
    unsigned short* hb     = (unsigned short*)(ws + (14u << 20));   // [N,128] 12.8 MB
    unsigned short* mean1b = (unsigned short*)(ws + (27u << 20));   // [N,64]  (dead after gemm1)
    unsigned short* mean2b = (unsigned short*)(ws + (27u << 20));   // [N,128] reuses mean1b region
    unsigned short* zb     = (unsigned short*)(ws + (40u << 20));   // [N,128] 12.8 MB

    unsigned short* W1lb  = wb;
    unsigned short* W1rb  = wb + 8192;
    unsigned short* W2lb  = wb + 16384;
    unsigned short* W2rb  = wb + 32768;
    unsigned short* Wrecb = wb + 49152;

    hipMemsetAsync(deg, 0, N_NODES * sizeof(int), stream);
    hipMemsetAsync(cursor, 0, N_NODES * sizeof(int), stream);

    int egrid = (N_EDGES + 255) / 256;
    int ngrid = (N_NODES + 63) / 64;   // 782

    k_cvt_w<<<56, 256, 0, stream>>>(W1l, W1r, W2l, W2r, Wrec, wb);
    k_cvt<<<(800000 + 255) / 256, 256, 0, stream>>>(x, xb, 800000);

    k_deg<<<egrid, 256, 0, stream>>>(ei, deg);
    k_scan1<<<NB_SCAN, 256, 0, stream>>>(deg, excl, bsum);
    k_scan2<<<1, 256, 0, stream>>>(bsum, bpre, offs);
    k_scan3<<<NB_SCAN, 256, 0, stream>>>(excl, bpre, offs);
    k_fill<<<egrid, 256, 0, stream>>>(ei, offs, cursor, csr);

    k_agg64b<<<N_NODES / 4, 256, 0, stream>>>(xb, csr, offs, mean1b);
    k_gemm_mfma<128, 128, true, true, false, true>
        <<<ngrid, 256, 0, stream>>>(mean1b, xb, W1lb, W1rb, b1l, nullptr, hb);
    k_agg128b<<<N_NODES / 4, 256, 0, stream>>>(hb, csr, offs, mean2b);
    k_gemm_mfma<128, 256, true, false, true, true>
        <<<ngrid, 256, 0, stream>>>(mean2b, hb, W2lb, W2rb, b2l, z, zb);
    k_gemm_mfma<64, 128, false, false, true, false>
        <<<ngrid, 256, 0, stream>>>(zb, nullptr, Wrecb, nullptr, brec, xrec, nullptr);
}